// Round 4
// baseline (1710.644 us; speedup 1.0000x reference)
//
#include <hip/hip_runtime.h>

#define BS 4
#define SEQL 8192
#define EMB 512
#define NH 8
#define HD 64
#define LM 64
#define SEG 128
#define BH (BS*NH)           // 32
#define NCH 16
#define CHS (SEQL/NCH)       // 512
#define QSCALE 0.35355339059327373f  // 64^(-1/4)

typedef unsigned short u16;

__device__ __forceinline__ float bf2f(u16 u) {
  return __uint_as_float(((unsigned int)u) << 16);
}
__device__ __forceinline__ u16 f2bf(float f) {
  unsigned int u = __float_as_uint(f);
  u += 0x7fffu + ((u >> 16) & 1u);   // RNE
  return (u16)(u >> 16);
}
// dtype-agnostic loads: isf32 chosen at runtime by probe_kernel (wave-uniform)
__device__ __forceinline__ float load1_any(const void* p, size_t idx, int isf32) {
  return isf32 ? ((const float*)p)[idx] : bf2f(((const u16*)p)[idx]);
}
__device__ __forceinline__ void load4_any(const void* p, size_t idx, int isf32, float* dst) {
  if (isf32) {
    float4 v = *reinterpret_cast<const float4*>((const float*)p + idx);
    dst[0] = v.x; dst[1] = v.y; dst[2] = v.z; dst[3] = v.w;
  } else {
    ushort4 v = *reinterpret_cast<const ushort4*>((const u16*)p + idx);
    dst[0] = bf2f(v.x); dst[1] = bf2f(v.y); dst[2] = bf2f(v.z); dst[3] = bf2f(v.w);
  }
}

// ------------------------------------------------------------- dtype probe
// bf16 N(0,1) data: even-indexed u16 exponent field never >= 134 (|v| >= 128).
// fp32 data read as u16 pairs: even index = low mantissa bits -> uniform -> ~47% hits.
__global__ __launch_bounds__(256) void probe_kernel(const void* x, int* flag) {
  __shared__ int cnt;
  if (threadIdx.x == 0) cnt = 0;
  __syncthreads();
  const u16* p = (const u16*)x;
  int c = 0;
  for (int j = 0; j < 16; j++) {
    u16 u = p[(size_t)(threadIdx.x * 16 + j) * 2];
    int e = (u >> 7) & 0xFF;
    if (e >= 134) c++;
  }
  atomicAdd(&cnt, c);
  __syncthreads();
  if (threadIdx.x == 0) flag[0] = (cnt > 256) ? 1 : 0;
}

// ------------------------------------------------------------- xmean (segment means of x)
// mean over each 128-row segment; landmark projections derive by linearity:
// mean(x@W+b) = mean(x)@W + b
__global__ __launch_bounds__(256) void xmean_kernel(const void* x, const int* flag,
                                                    float* __restrict__ xmean) {
  const int bl = blockIdx.x;          // b*64 + l  (global row = bl*128 + r)
  const int t = threadIdx.x;
  const int isf32 = flag[0];
  const int c = t * 2;
  const size_t base = (size_t)bl * SEG * EMB;
  float s0 = 0.f, s1 = 0.f;
  for (int r = 0; r < SEG; r++) {
    size_t idx = base + (size_t)r * EMB + c;
    if (isf32) {
      float2 v = *reinterpret_cast<const float2*>((const float*)x + idx);
      s0 += v.x; s1 += v.y;
    } else {
      ushort2 v = *reinterpret_cast<const ushort2*>((const u16*)x + idx);
      s0 += bf2f(v.x); s1 += bf2f(v.y);
    }
  }
  xmean[(size_t)bl * EMB + c]     = s0 * (1.0f / SEG);
  xmean[(size_t)bl * EMB + c + 1] = s1 * (1.0f / SEG);
}

// ------------------------------------------------------------- landmark projections
// qL/kL[bh][l][d] = (xmean[b,l,:] @ W[:, h*64+d] + bias[h*64+d]) * QSCALE
__global__ __launch_bounds__(256) void lm_proj_kernel(
    const float* __restrict__ xmean,
    const void* Wq, const void* bq, const void* Wk, const void* bk,
    const int* flag, float* __restrict__ qL, float* __restrict__ kL)
{
  __shared__ float As[64 * 17];
  __shared__ float Bs[16 * 64];
  const int t = threadIdx.x;
  const int m0 = blockIdx.x * 64, n0 = blockIdx.y * 64, z = blockIdx.z;
  const void* W    = z ? Wk : Wq;
  const void* bias = z ? bk : bq;
  float* dst       = z ? kL : qL;
  const int isf32 = flag[0];
  const int tx = t & 15, ty = t >> 4;
  const int arow = t >> 2, akk = (t & 3) << 2;
  const int brow = t >> 4, bcol = (t & 15) << 2;
  float acc[4][4] = {};
  for (int k0 = 0; k0 < EMB; k0 += 16) {
    float4 av = *reinterpret_cast<const float4*>(xmean + (size_t)(m0 + arow) * EMB + k0 + akk);
    As[arow * 17 + akk + 0] = av.x;
    As[arow * 17 + akk + 1] = av.y;
    As[arow * 17 + akk + 2] = av.z;
    As[arow * 17 + akk + 3] = av.w;
    load4_any(W, (size_t)(k0 + brow) * EMB + n0 + bcol, isf32, &Bs[brow * 64 + bcol]);
    __syncthreads();
    #pragma unroll
    for (int kk = 0; kk < 16; kk++) {
      float a[4], b[4];
      #pragma unroll
      for (int i = 0; i < 4; i++) a[i] = As[(ty * 4 + i) * 17 + kk];
      #pragma unroll
      for (int j = 0; j < 4; j++) b[j] = Bs[kk * 64 + tx * 4 + j];
      #pragma unroll
      for (int i = 0; i < 4; i++)
        #pragma unroll
        for (int j = 0; j < 4; j++)
          acc[i][j] = fmaf(a[i], b[j], acc[i][j]);
    }
    __syncthreads();
  }
  #pragma unroll
  for (int i = 0; i < 4; i++) {
    int m = m0 + ty * 4 + i;
    int b = m >> 6, l = m & 63;
    #pragma unroll
    for (int j = 0; j < 4; j++) {
      int n = n0 + tx * 4 + j;
      int h = n >> 6, d = n & 63;
      float c = (acc[i][j] + load1_any(bias, n, isf32)) * QSCALE;
      dst[(size_t)((b * NH + h) * LM + l) * HD + d] = c;
    }
  }
}

// ------------------------------------------------------------- kernel_2 softmax + colsums
__global__ __launch_bounds__(256) void k2_softmax_kernel(
    const float* __restrict__ qL, const float* __restrict__ kL,
    float* __restrict__ K2, float* __restrict__ cs)
{
  __shared__ float qs[64 * 65], ks[64 * 65], ps[64 * 65];
  const int t = threadIdx.x, bh = blockIdx.x;
  const int r = t >> 2, cb = (t & 3) << 4;
  #pragma unroll
  for (int i = 0; i < 16; i++) {
    qs[r * 65 + cb + i] = qL[((size_t)bh * LM + r) * HD + cb + i];
    ks[r * 65 + cb + i] = kL[((size_t)bh * LM + r) * HD + cb + i];
  }
  __syncthreads();
  float lg[16] = {};
  for (int d = 0; d < HD; d++) {
    float a = qs[r * 65 + d];
    #pragma unroll
    for (int i = 0; i < 16; i++) lg[i] = fmaf(a, ks[(cb + i) * 65 + d], lg[i]);
  }
  float m = lg[0];
  #pragma unroll
  for (int i = 1; i < 16; i++) m = fmaxf(m, lg[i]);
  m = fmaxf(m, __shfl_xor(m, 1));
  m = fmaxf(m, __shfl_xor(m, 2));
  float s = 0.f;
  #pragma unroll
  for (int i = 0; i < 16; i++) { lg[i] = __expf(lg[i] - m); s += lg[i]; }
  s += __shfl_xor(s, 1);
  s += __shfl_xor(s, 2);
  const float inv = 1.0f / s;
  #pragma unroll
  for (int i = 0; i < 16; i++) {
    float p = lg[i] * inv;
    ps[r * 65 + cb + i] = p;
    K2[((size_t)bh * LM + r) * LM + cb + i] = p;
  }
  __syncthreads();
  if (t < 64) {
    float c = 0.f;
    for (int rr = 0; rr < 64; rr++) c += ps[rr * 65 + t];
    cs[bh * LM + t] = c;
  }
}

// ------------------------------------------------------------- Newton-Schulz inverse
__device__ __forceinline__ void mm64(const float* A, const float* B, float* C, int t) {
  const int r = t >> 2, cb = (t & 3) << 4;
  float o[16] = {};
  for (int k = 0; k < 64; k++) {
    float a = A[r * 64 + k];
    #pragma unroll
    for (int i = 0; i < 16; i++) o[i] = fmaf(a, B[k * 64 + cb + i], o[i]);
  }
  #pragma unroll
  for (int i = 0; i < 16; i++) C[r * 64 + cb + i] = o[i];
}

__global__ __launch_bounds__(256) void ns_inverse_kernel(
    const float* __restrict__ K2, const float* __restrict__ cs,
    float* __restrict__ Vi)
{
  __shared__ float Vv[64 * 64], B1[64 * 64], B2[64 * 64], B3[64 * 64];
  const int t = threadIdx.x, bh = blockIdx.x;
  const int r = t >> 2, cb = (t & 3) << 4;

  // global max over ALL (b,h) column sums (matches jnp.max over all axes)
  float m = -1e30f;
  for (int i = t; i < BH * LM; i += 256) m = fmaxf(m, cs[i]);
  B3[t] = m;
  __syncthreads();
  for (int off = 128; off; off >>= 1) {
    if (t < off) B3[t] = fmaxf(B3[t], B3[t + off]);
    __syncthreads();
  }
  const float ginv = 1.0f / B3[0];
  __syncthreads();

  // V0 = K2^T * ginv
  #pragma unroll
  for (int i = 0; i < 16; i++) B1[r * 64 + cb + i] = K2[((size_t)bh * LM + r) * LM + cb + i];
  __syncthreads();
  #pragma unroll
  for (int i = 0; i < 16; i++) Vv[r * 64 + cb + i] = B1[(cb + i) * 64 + r] * ginv;
  __syncthreads();

  for (int it = 0; it < 6; it++) {
    #pragma unroll
    for (int i = 0; i < 16; i++) B1[r * 64 + cb + i] = K2[((size_t)bh * LM + r) * LM + cb + i];
    __syncthreads();
    mm64(B1, Vv, B2, t);                   // B2 = K V
    __syncthreads();
    #pragma unroll
    for (int i = 0; i < 16; i++) {
      int c = cb + i;
      B1[r * 64 + c] = (r == c ? 7.0f : 0.0f) - B2[r * 64 + c];    // 7I - KV
    }
    __syncthreads();
    mm64(B2, B1, B3, t);                   // B3 = KV(7I-KV)
    __syncthreads();
    #pragma unroll
    for (int i = 0; i < 16; i++) {
      int c = cb + i;
      B3[r * 64 + c] = (r == c ? 15.0f : 0.0f) - B3[r * 64 + c];   // 15I - ...
    }
    __syncthreads();
    mm64(B2, B3, B1, t);                   // B1 = KV(15I-...)
    __syncthreads();
    #pragma unroll
    for (int i = 0; i < 16; i++) {
      int c = cb + i;
      B1[r * 64 + c] = (r == c ? 13.0f : 0.0f) - B1[r * 64 + c];   // 13I - ...
    }
    __syncthreads();
    mm64(Vv, B1, B3, t);                   // B3 = V(13I-...)
    __syncthreads();
    #pragma unroll
    for (int i = 0; i < 16; i++) Vv[r * 64 + cb + i] = 0.25f * B3[r * 64 + cb + i];
    __syncthreads();
  }
  #pragma unroll
  for (int i = 0; i < 16; i++) Vi[((size_t)bh * LM + r) * LM + cb + i] = Vv[r * 64 + cb + i];
}

// ------------------------------------------------------------- fused K/V projection + kernel_3 @ v
// per (bh, chunk): streams 512 x-rows, builds k,v tiles on the fly,
// accumulates num = exp(qL k^T) v and den = rowsum into split-K partials.
__global__ __launch_bounds__(256) void k3v_fused_kernel(
    const void* x, const void* Wk, const void* bk, const void* Wv, const void* bv,
    const float* __restrict__ qL, const int* flag,
    float* __restrict__ pnum, float* __restrict__ pden)
{
  __shared__ float sm[15616];
  float* qLs = sm;           // 64x65
  float* kc  = sm + 4160;    // 64x65 (reused as exp(S))
  float* vc  = sm + 8320;    // 64x65
  float* xs  = sm + 12480;   // 64x17
  float* wks = sm + 13568;   // 16x64
  float* wvs = sm + 14592;   // 16x64
  const int t = threadIdx.x;
  const int bh = blockIdx.x, ch = blockIdx.y;
  const int b = bh >> 3, h = bh & 7;
  const int isf32 = flag[0];
  const int tx = t & 15, ty = t >> 4;
  const int r = t >> 2, cb = (t & 3) << 4;
  const int arow = t >> 2, akk = (t & 3) << 2;
  const int brow = t >> 4, bcol = (t & 15) << 2;

  #pragma unroll
  for (int i = 0; i < 16; i++) qLs[r * 65 + cb + i] = qL[((size_t)bh * LM + r) * HD + cb + i];
  float bkv[4], bvv[4];
  #pragma unroll
  for (int j = 0; j < 4; j++) {
    bkv[j] = load1_any(bk, h * 64 + tx * 4 + j, isf32);
    bvv[j] = load1_any(bv, h * 64 + tx * 4 + j, isf32);
  }
  float num[16] = {};
  float den = 0.f;

  for (int sub = 0; sub < 8; sub++) {
    const size_t row0 = (size_t)b * SEQL + (size_t)ch * CHS + sub * 64;
    float acck[4][4] = {}, accv[4][4] = {};
    for (int k0 = 0; k0 < EMB; k0 += 16) {
      __syncthreads();
      load4_any(x, (row0 + arow) * EMB + k0 + akk, isf32, &xs[arow * 17 + akk]);
      load4_any(Wk, (size_t)(k0 + brow) * EMB + h * 64 + bcol, isf32, &wks[brow * 64 + bcol]);
      load4_any(Wv, (size_t)(k0 + brow) * EMB + h * 64 + bcol, isf32, &wvs[brow * 64 + bcol]);
      __syncthreads();
      #pragma unroll
      for (int kk = 0; kk < 16; kk++) {
        float a[4], bk_[4], bv_[4];
        #pragma unroll
        for (int i = 0; i < 4; i++) a[i] = xs[(ty * 4 + i) * 17 + kk];
        #pragma unroll
        for (int j = 0; j < 4; j++) { bk_[j] = wks[kk * 64 + tx * 4 + j]; bv_[j] = wvs[kk * 64 + tx * 4 + j]; }
        #pragma unroll
        for (int i = 0; i < 4; i++)
          #pragma unroll
          for (int j = 0; j < 4; j++) {
            acck[i][j] = fmaf(a[i], bk_[j], acck[i][j]);
            accv[i][j] = fmaf(a[i], bv_[j], accv[i][j]);
          }
      }
    }
    __syncthreads();
    #pragma unroll
    for (int i = 0; i < 4; i++)
      #pragma unroll
      for (int j = 0; j < 4; j++) {
        kc[(ty * 4 + i) * 65 + tx * 4 + j] = (acck[i][j] + bkv[j]) * QSCALE;
        vc[(ty * 4 + i) * 65 + tx * 4 + j] = accv[i][j] + bvv[j];
      }
    __syncthreads();
    float lg[16] = {};
    for (int d = 0; d < HD; d++) {
      float a = qLs[r * 65 + d];
      #pragma unroll
      for (int i = 0; i < 16; i++) lg[i] = fmaf(a, kc[(cb + i) * 65 + d], lg[i]);
    }
    __syncthreads();
    // logits ~ N(0, ~0.01): exp without max-subtraction is numerically safe
    #pragma unroll
    for (int i = 0; i < 16; i++) kc[r * 65 + cb + i] = __expf(lg[i]);
    __syncthreads();
    for (int sc = 0; sc < 64; sc++) {
      float w = kc[r * 65 + sc];
      den += w;
      #pragma unroll
      for (int i = 0; i < 16; i++) num[i] = fmaf(w, vc[sc * 65 + cb + i], num[i]);
    }
  }
  #pragma unroll
  for (int i = 0; i < 16; i++)
    pnum[(((size_t)bh * NCH + ch) * LM + r) * HD + cb + i] = num[i];
  if ((t & 3) == 0) pden[((size_t)bh * NCH + ch) * LM + r] = den;
}

// ------------------------------------------------------------- reduce partials; W2 = Vi @ normalize(k3 v)
__global__ __launch_bounds__(256) void k3v_w2_kernel(
    const float* __restrict__ pnum, const float* __restrict__ pden,
    const float* __restrict__ Vi, float* __restrict__ W2)
{
  __shared__ float Vs[64 * 65], Ms[64 * 65], den[64];
  const int t = threadIdx.x, bh = blockIdx.x;
  const int r = t >> 2, cb = (t & 3) << 4;
  #pragma unroll
  for (int i = 0; i < 16; i++) Vs[r * 65 + cb + i] = Vi[((size_t)bh * LM + r) * LM + cb + i];
  float acc[16] = {};
  for (int ch = 0; ch < NCH; ch++) {
    const float* p = pnum + (((size_t)bh * NCH + ch) * LM + r) * HD + cb;
    #pragma unroll
    for (int i = 0; i < 16; i++) acc[i] += p[i];
  }
  if ((t & 3) == 0) {
    float d = 0.f;
    for (int ch = 0; ch < NCH; ch++) d += pden[((size_t)bh * NCH + ch) * LM + r];
    den[r] = d;
  }
  __syncthreads();
  const float dinv = 1.0f / den[r];
  #pragma unroll
  for (int i = 0; i < 16; i++) Ms[r * 65 + cb + i] = acc[i] * dinv;
  __syncthreads();
  float o[16] = {};
  for (int k = 0; k < 64; k++) {
    float a = Vs[r * 65 + k];
    #pragma unroll
    for (int i = 0; i < 16; i++) o[i] = fmaf(a, Ms[k * 65 + cb + i], o[i]);
  }
  #pragma unroll
  for (int i = 0; i < 16; i++) W2[((size_t)bh * LM + r) * HD + cb + i] = o[i];
}

// ------------------------------------------------------------- fused Q projection + kernel_1 @ W2
__global__ __launch_bounds__(256) void final_fused_kernel(
    const void* x, const void* Wq, const void* bq,
    const float* __restrict__ kL, const float* __restrict__ W2,
    const int* flag, u16* __restrict__ pre)
{
  __shared__ float sm[14592];
  float* qc  = sm;           // 64x65 (then reused as P)
  float* kLs = sm + 4160;    // 64x65
  float* W2s = sm + 8320;    // 64x65
  float* xs  = sm + 12480;   // 64x17
  float* wqs = sm + 13568;   // 16x64
  const int t = threadIdx.x;
  const int h = blockIdx.x, mch = blockIdx.y;
  const int m0 = mch * 64;              // global row in [0, 32768)
  const int b = m0 >> 13;
  const int bh = b * NH + h;
  const int isf32 = flag[0];
  const int tx = t & 15, ty = t >> 4;
  const int r = t >> 2, cb = (t & 3) << 4;
  const int arow = t >> 2, akk = (t & 3) << 2;
  const int brow = t >> 4, bcol = (t & 15) << 2;

  #pragma unroll
  for (int i = 0; i < 16; i++) {
    kLs[r * 65 + cb + i] = kL[((size_t)bh * LM + r) * HD + cb + i];
    W2s[r * 65 + cb + i] = W2[((size_t)bh * LM + r) * HD + cb + i];
  }
  float bqv[4];
  #pragma unroll
  for (int j = 0; j < 4; j++) bqv[j] = load1_any(bq, h * 64 + tx * 4 + j, isf32);

  float acc[4][4] = {};
  for (int k0 = 0; k0 < EMB; k0 += 16) {
    __syncthreads();
    load4_any(x, (size_t)(m0 + arow) * EMB + k0 + akk, isf32, &xs[arow * 17 + akk]);
    load4_any(Wq, (size_t)(k0 + brow) * EMB + h * 64 + bcol, isf32, &wqs[brow * 64 + bcol]);
    __syncthreads();
    #pragma unroll
    for (int kk = 0; kk < 16; kk++) {
      float a[4], w[4];
      #pragma unroll
      for (int i = 0; i < 4; i++) a[i] = xs[(ty * 4 + i) * 17 + kk];
      #pragma unroll
      for (int j = 0; j < 4; j++) w[j] = wqs[kk * 64 + tx * 4 + j];
      #pragma unroll
      for (int i = 0; i < 4; i++)
        #pragma unroll
        for (int j = 0; j < 4; j++)
          acc[i][j] = fmaf(a[i], w[j], acc[i][j]);
    }
  }
  __syncthreads();
  #pragma unroll
  for (int i = 0; i < 4; i++)
    #pragma unroll
    for (int j = 0; j < 4; j++)
      qc[(ty * 4 + i) * 65 + tx * 4 + j] = (acc[i][j] + bqv[j]) * QSCALE;
  __syncthreads();
  float lg[16] = {};
  for (int d = 0; d < HD; d++) {
    float a = qc[r * 65 + d];
    #pragma unroll
    for (int i = 0; i < 16; i++) lg[i] = fmaf(a, kLs[(cb + i) * 65 + d], lg[i]);
  }
  float m = lg[0];
  #pragma unroll
  for (int i = 1; i < 16; i++) m = fmaxf(m, lg[i]);
  m = fmaxf(m, __shfl_xor(m, 1));
  m = fmaxf(m, __shfl_xor(m, 2));
  float s = 0.f;
  #pragma unroll
  for (int i = 0; i < 16; i++) { lg[i] = __expf(lg[i] - m); s += lg[i]; }
  s += __shfl_xor(s, 1);
  s += __shfl_xor(s, 2);
  const float inv = 1.0f / s;
  __syncthreads();
  #pragma unroll
  for (int i = 0; i < 16; i++) qc[r * 65 + cb + i] = lg[i] * inv;
  __syncthreads();
  float o[16] = {};
  for (int l = 0; l < 64; l++) {
    float p = qc[r * 65 + l];
    #pragma unroll
    for (int i = 0; i < 16; i++) o[i] = fmaf(p, W2s[l * 65 + cb + i], o[i]);
  }
  u16* op = pre + (size_t)(m0 + r) * EMB + h * HD + cb;
  #pragma unroll
  for (int i = 0; i < 16; i++) op[i] = f2bf(o[i]);
}

// ------------------------------------------------------------- out = pre @ Wo + bo
__global__ __launch_bounds__(256) void out_proj_kernel(
    const u16* __restrict__ pre, const void* Wo, const void* bo,
    const int* flag, void* out)
{
  __shared__ float As[64 * 17];
  __shared__ float Bs[16 * 64];
  const int t = threadIdx.x;
  const int m0 = blockIdx.x * 64, n0 = blockIdx.y * 64;
  const int isf32 = flag[0];
  const int tx = t & 15, ty = t >> 4;
  const int arow = t >> 2, akk = (t & 3) << 2;
  const int brow = t >> 4, bcol = (t & 15) << 2;
  float acc[4][4] = {};
  for (int k0 = 0; k0 < EMB; k0 += 16) {
    ushort4 av = *reinterpret_cast<const ushort4*>(pre + (size_t)(m0 + arow) * EMB + k0 + akk);
    As[arow * 17 + akk + 0] = bf2f(av.x);
    As[arow * 17 + akk + 1] = bf2f(av.y);
    As[arow * 17 + akk + 2] = bf2f(av.z);
    As[arow * 17 + akk + 3] = bf2f(av.w);
    load4_any(Wo, (size_t)(k0 + brow) * EMB + n0 + bcol, isf32, &Bs[brow * 64 + bcol]);
    __syncthreads();
    #pragma unroll
    for (int kk = 0; kk < 16; kk++) {
      float a[4], b[4];
      #pragma unroll
      for (int i = 0; i < 4; i++) a[i] = As[(ty * 4 + i) * 17 + kk];
      #pragma unroll
      for (int j = 0; j < 4; j++) b[j] = Bs[kk * 64 + tx * 4 + j];
      #pragma unroll
      for (int i = 0; i < 4; i++)
        #pragma unroll
        for (int j = 0; j < 4; j++)
          acc[i][j] = fmaf(a[i], b[j], acc[i][j]);
    }
    __syncthreads();
  }
  #pragma unroll
  for (int i = 0; i < 4; i++) {
    int m = m0 + ty * 4 + i;
    #pragma unroll
    for (int j = 0; j < 4; j++) {
      int n = n0 + tx * 4 + j;
      float v = acc[i][j] + load1_any(bo, n, isf32);
      if (isf32) ((float*)out)[(size_t)m * EMB + n] = v;
      else       ((u16*)out)[(size_t)m * EMB + n] = f2bf(v);
    }
  }
}

// ------------------------------------------------------------- launch
extern "C" void kernel_launch(void* const* d_in, const int* in_sizes, int n_in,
                              void* d_out, int out_size, void* d_ws, size_t ws_size,
                              hipStream_t stream)
{
  (void)in_sizes; (void)n_in; (void)out_size; (void)ws_size;
  const void* x  = d_in[0];
  const void* Wq = d_in[1];
  const void* bq = d_in[2];
  const void* Wk = d_in[3];
  const void* bk = d_in[4];
  const void* Wv = d_in[5];
  const void* bv = d_in[6];
  const void* Wo = d_in[7];
  const void* bo = d_in[8];

  float* ws = (float*)d_ws;
  int*   flag  = (int*)ws;                       // 64 floats reserved
  float* xmean = ws + 64;                        // 131072 floats
  float* qL    = xmean + (size_t)BS * LM * EMB;  // 131072
  float* kL    = qL + (size_t)BH * LM * HD;      // 131072
  float* K2    = kL + (size_t)BH * LM * HD;      // 131072
  float* cs    = K2 + (size_t)BH * LM * LM;      // 2048
  float* Vi    = cs + (size_t)BH * LM;           // 131072
  float* W2    = Vi + (size_t)BH * LM * LM;      // 131072
  float* pnum  = W2 + (size_t)BH * LM * HD;      // 2097152 floats
  float* pden  = pnum + (size_t)BH * NCH * LM * HD;  // 32768 floats
  // pre ALIASES pnum: pnum/pden are dead after k3v_w2_kernel, and
  // final_fused_kernel (which writes pre) runs strictly after it.
  u16*   pre   = (u16*)pnum;                     // 16777216 u16 = 33.5 MB
  // total ws footprint: 3.7 MB prefix + 33.5 MB = ~37.2 MB

  probe_kernel<<<1, 256, 0, stream>>>(x, (int*)flag);
  xmean_kernel<<<BS * LM, 256, 0, stream>>>(x, flag, xmean);
  lm_proj_kernel<<<dim3(4, 8, 2), 256, 0, stream>>>(xmean, Wq, bq, Wk, bk, flag, qL, kL);
  k2_softmax_kernel<<<BH, 256, 0, stream>>>(qL, kL, K2, cs);
  ns_inverse_kernel<<<BH, 256, 0, stream>>>(K2, cs, Vi);
  k3v_fused_kernel<<<dim3(BH, NCH), 256, 0, stream>>>(x, Wk, bk, Wv, bv, qL, flag, pnum, pden);
  k3v_w2_kernel<<<BH, 256, 0, stream>>>(pnum, pden, Vi, W2);
  final_fused_kernel<<<dim3(NH, SEQL * BS / 64), 256, 0, stream>>>(x, Wq, bq, kL, W2, flag, pre);
  out_proj_kernel<<<dim3(512, 8), 256, 0, stream>>>(pre, Wo, bo, flag, d_out);
}

// Round 6
// 566.810 us; speedup vs baseline: 3.0180x; 3.0180x over previous
//
#include <hip/hip_runtime.h>

#define BS 4
#define SEQL 8192
#define EMB 512
#define NH 8
#define HD 64
#define LM 64
#define SEG 128
#define BH (BS*NH)           // 32
#define NCH 16
#define CHS (SEQL/NCH)       // 512
#define QSCALE 0.35355339059327373f  // 64^(-1/4)

typedef unsigned short u16;
typedef __bf16 bf16_t;
typedef __attribute__((ext_vector_type(8))) __bf16 bf16x8;
typedef __attribute__((ext_vector_type(4))) float f32x4;

#define MFMA16(a, b, c) __builtin_amdgcn_mfma_f32_16x16x32_bf16((a), (b), (c), 0, 0, 0)

__device__ __forceinline__ float bf2f(u16 u) {
  return __uint_as_float(((unsigned int)u) << 16);
}
__device__ __forceinline__ u16 f2bf(float f) {
  unsigned int u = __float_as_uint(f);
  u += 0x7fffu + ((u >> 16) & 1u);   // RNE
  return (u16)(u >> 16);
}
__device__ __forceinline__ float load1_any(const void* p, size_t idx, int isf32) {
  return isf32 ? ((const float*)p)[idx] : bf2f(((const u16*)p)[idx]);
}
__device__ __forceinline__ void load4_any(const void* p, size_t idx, int isf32, float* dst) {
  if (isf32) {
    float4 v = *reinterpret_cast<const float4*>((const float*)p + idx);
    dst[0] = v.x; dst[1] = v.y; dst[2] = v.z; dst[3] = v.w;
  } else {
    ushort4 v = *reinterpret_cast<const ushort4*>((const u16*)p + idx);
    dst[0] = bf2f(v.x); dst[1] = bf2f(v.y); dst[2] = bf2f(v.z); dst[3] = bf2f(v.w);
  }
}
// load 8 consecutive source elems as bf16 bit patterns into o[8]
__device__ __forceinline__ void ld8_bf(const void* p, size_t idx, int isf32, u16* o) {
  if (isf32) {
    const float* f = (const float*)p + idx;
    float4 a = *reinterpret_cast<const float4*>(f);
    float4 b = *reinterpret_cast<const float4*>(f + 4);
    o[0] = f2bf(a.x); o[1] = f2bf(a.y); o[2] = f2bf(a.z); o[3] = f2bf(a.w);
    o[4] = f2bf(b.x); o[5] = f2bf(b.y); o[6] = f2bf(b.z); o[7] = f2bf(b.w);
  } else {
    *reinterpret_cast<int4*>(o) = *reinterpret_cast<const int4*>((const u16*)p + idx);
  }
}

// ------------------------------------------------------------- dtype probe
__global__ __launch_bounds__(256) void probe_kernel(const void* x, int* flag) {
  __shared__ int cnt;
  if (threadIdx.x == 0) cnt = 0;
  __syncthreads();
  const u16* p = (const u16*)x;
  int c = 0;
  for (int j = 0; j < 16; j++) {
    u16 u = p[(size_t)(threadIdx.x * 16 + j) * 2];
    int e = (u >> 7) & 0xFF;
    if (e >= 134) c++;
  }
  atomicAdd(&cnt, c);
  __syncthreads();
  if (threadIdx.x == 0) flag[0] = (cnt > 256) ? 1 : 0;
}

// ------------------------------------------------------------- weight transposes -> bf16 WT[n][k]
// 64x64 tile per block; 256 threads: r = t>>2 in [0,64), col quarter = (t&3)*16.
__global__ __launch_bounds__(256) void prep_wt_kernel(
    const void* Wq, const void* Wk, const void* Wv, const void* Wo, const int* flag,
    u16* __restrict__ WqT, u16* __restrict__ WkT, u16* __restrict__ WvT, u16* __restrict__ WoT)
{
  __shared__ u16 Ws[64 * 72];
  const int id = blockIdx.x;
  const int z = id >> 6, tile = id & 63;
  const int k0 = (tile >> 3) * 64, n0 = (tile & 7) * 64;
  const void* W = (z == 0) ? Wq : (z == 1) ? Wk : (z == 2) ? Wv : Wo;
  u16* WT = (z == 0) ? WqT : (z == 1) ? WkT : (z == 2) ? WvT : WoT;
  const int isf32 = flag[0];
  const int t = threadIdx.x;
  const int r = t >> 2, cq = (t & 3) * 16;
  u16 tmp[8];
  #pragma unroll
  for (int u = 0; u < 2; u++) {
    ld8_bf(W, (size_t)(k0 + r) * EMB + n0 + cq + 8 * u, isf32, tmp);
    *reinterpret_cast<int4*>(&Ws[r * 72 + cq + 8 * u]) = *reinterpret_cast<int4*>(tmp);
  }
  __syncthreads();
  // write row nn of WT: gather column nn of Ws
  const int nn = t >> 2, kq = (t & 3) * 16;
  #pragma unroll
  for (int u = 0; u < 2; u++) {
    u16 o[8];
    #pragma unroll
    for (int j = 0; j < 8; j++) o[j] = Ws[(kq + 8 * u + j) * 72 + nn];
    *reinterpret_cast<int4*>(&WT[(size_t)(n0 + nn) * EMB + k0 + kq + 8 * u]) =
        *reinterpret_cast<int4*>(o);
  }
}

// ------------------------------------------------------------- xmean
__global__ __launch_bounds__(256) void xmean_kernel(const void* x, const int* flag,
                                                    float* __restrict__ xmean) {
  const int bl = blockIdx.x;
  const int t = threadIdx.x;
  const int isf32 = flag[0];
  const int c = t * 2;
  const size_t base = (size_t)bl * SEG * EMB;
  float s0 = 0.f, s1 = 0.f;
  for (int r = 0; r < SEG; r++) {
    size_t idx = base + (size_t)r * EMB + c;
    if (isf32) {
      float2 v = *reinterpret_cast<const float2*>((const float*)x + idx);
      s0 += v.x; s1 += v.y;
    } else {
      ushort2 v = *reinterpret_cast<const ushort2*>((const u16*)x + idx);
      s0 += bf2f(v.x); s1 += bf2f(v.y);
    }
  }
  xmean[(size_t)bl * EMB + c]     = s0 * (1.0f / SEG);
  xmean[(size_t)bl * EMB + c + 1] = s1 * (1.0f / SEG);
}

// ------------------------------------------------------------- landmark projections (fp32 + bf16 copies)
__global__ __launch_bounds__(256) void lm_proj_kernel(
    const float* __restrict__ xmean,
    const void* Wq, const void* bq, const void* Wk, const void* bk,
    const int* flag, float* __restrict__ qL, float* __restrict__ kL,
    u16* __restrict__ qLb, u16* __restrict__ kLb)
{
  __shared__ float As[64 * 17];
  __shared__ float Bs[16 * 64];
  const int t = threadIdx.x;
  const int m0 = blockIdx.x * 64, n0 = blockIdx.y * 64, z = blockIdx.z;
  const void* W    = z ? Wk : Wq;
  const void* bias = z ? bk : bq;
  float* dst       = z ? kL : qL;
  u16*   dstb      = z ? kLb : qLb;
  const int isf32 = flag[0];
  const int tx = t & 15, ty = t >> 4;
  const int arow = t >> 2, akk = (t & 3) << 2;
  const int brow = t >> 4, bcol = (t & 15) << 2;
  float acc[4][4] = {};
  for (int k0 = 0; k0 < EMB; k0 += 16) {
    float4 av = *reinterpret_cast<const float4*>(xmean + (size_t)(m0 + arow) * EMB + k0 + akk);
    As[arow * 17 + akk + 0] = av.x;
    As[arow * 17 + akk + 1] = av.y;
    As[arow * 17 + akk + 2] = av.z;
    As[arow * 17 + akk + 3] = av.w;
    load4_any(W, (size_t)(k0 + brow) * EMB + n0 + bcol, isf32, &Bs[brow * 64 + bcol]);
    __syncthreads();
    #pragma unroll
    for (int kk = 0; kk < 16; kk++) {
      float a[4], b[4];
      #pragma unroll
      for (int i = 0; i < 4; i++) a[i] = As[(ty * 4 + i) * 17 + kk];
      #pragma unroll
      for (int j = 0; j < 4; j++) b[j] = Bs[kk * 64 + tx * 4 + j];
      #pragma unroll
      for (int i = 0; i < 4; i++)
        #pragma unroll
        for (int j = 0; j < 4; j++)
          acc[i][j] = fmaf(a[i], b[j], acc[i][j]);
    }
    __syncthreads();
  }
  #pragma unroll
  for (int i = 0; i < 4; i++) {
    int m = m0 + ty * 4 + i;
    int b = m >> 6, l = m & 63;
    #pragma unroll
    for (int j = 0; j < 4; j++) {
      int n = n0 + tx * 4 + j;
      int h = n >> 6, d = n & 63;
      float c = (acc[i][j] + load1_any(bias, n, isf32)) * QSCALE;
      size_t idx = (size_t)((b * NH + h) * LM + l) * HD + d;
      dst[idx] = c;
      dstb[idx] = f2bf(c);
    }
  }
}

// ------------------------------------------------------------- MFMA QKV projection
// Qb/Kb: [bh][s][d] bf16 (scaled). V: stored transposed VbT [bh][d][s] bf16.
__global__ __launch_bounds__(256) void proj_qkv_kernel(
    const void* x, const u16* __restrict__ WqT, const u16* __restrict__ WkT,
    const u16* __restrict__ WvT,
    const void* bq, const void* bk, const void* bv, const int* flag,
    u16* __restrict__ Qb, u16* __restrict__ Kb, u16* __restrict__ VbT)
{
  __shared__ u16 smem[2 * 128 * 72];
  u16* As = smem;
  u16* Bs = smem + 128 * 72;
  const int t = threadIdx.x;
  const int m0 = blockIdx.x * 128, n0 = blockIdx.y * 128, z = blockIdx.z;
  const u16* WT = (z == 0) ? WqT : (z == 1) ? WkT : WvT;
  const void* bias = (z == 0) ? bq : (z == 1) ? bk : bv;
  const int isf32 = flag[0];
  const int w = t >> 6, lane = t & 63, q = lane >> 4, c = lane & 15;
  const int wm = (w >> 1) * 64, wn = (w & 1) * 64;
  const int sr = t >> 1, sh = (t & 1) * 32;

  f32x4 acc[4][4];
  f32x4 z4 = {0.f, 0.f, 0.f, 0.f};
  #pragma unroll
  for (int mi = 0; mi < 4; mi++)
    #pragma unroll
    for (int ni = 0; ni < 4; ni++) acc[mi][ni] = z4;

  for (int k0 = 0; k0 < EMB; k0 += 64) {
    __syncthreads();
    u16 tmp[8];
    #pragma unroll
    for (int u = 0; u < 4; u++) {
      ld8_bf(x, (size_t)(m0 + sr) * EMB + k0 + sh + 8 * u, isf32, tmp);
      *reinterpret_cast<int4*>(&As[sr * 72 + sh + 8 * u]) = *reinterpret_cast<int4*>(tmp);
    }
    #pragma unroll
    for (int u = 0; u < 4; u++) {
      *reinterpret_cast<int4*>(&Bs[sr * 72 + sh + 8 * u]) =
          *reinterpret_cast<const int4*>(&WT[(size_t)(n0 + sr) * EMB + k0 + sh + 8 * u]);
    }
    __syncthreads();
    #pragma unroll
    for (int kk = 0; kk < 64; kk += 32) {
      bf16x8 af[4], bfv[4];
      #pragma unroll
      for (int mi = 0; mi < 4; mi++)
        af[mi] = *reinterpret_cast<const bf16x8*>(&As[(wm + mi * 16 + c) * 72 + kk + q * 8]);
      #pragma unroll
      for (int ni = 0; ni < 4; ni++)
        bfv[ni] = *reinterpret_cast<const bf16x8*>(&Bs[(wn + ni * 16 + c) * 72 + kk + q * 8]);
      #pragma unroll
      for (int mi = 0; mi < 4; mi++)
        #pragma unroll
        for (int ni = 0; ni < 4; ni++)
          acc[mi][ni] = MFMA16(af[mi], bfv[ni], acc[mi][ni]);
    }
  }

  float bb[4];
  #pragma unroll
  for (int ni = 0; ni < 4; ni++) bb[ni] = load1_any(bias, n0 + wn + ni * 16 + c, isf32);

  if (z < 2) {
    const float scl = QSCALE;
    u16* dst = (z == 0) ? Qb : Kb;
    #pragma unroll
    for (int mi = 0; mi < 4; mi++)
      #pragma unroll
      for (int i = 0; i < 4; i++) {
        int m = m0 + wm + mi * 16 + q * 4 + i;
        int b = m >> 13, s = m & (SEQL - 1);
        #pragma unroll
        for (int ni = 0; ni < 4; ni++) {
          int n = n0 + wn + ni * 16 + c;
          int h = n >> 6, d = n & 63;
          dst[((size_t)((b * NH + h) * SEQL + s)) * HD + d] =
              f2bf((acc[mi][ni][i] + bb[ni]) * scl);
        }
      }
  } else {
    // transpose through LDS: Ct[n_local][m_local], pitch 136
    __syncthreads();
    #pragma unroll
    for (int mi = 0; mi < 4; mi++)
      #pragma unroll
      for (int i = 0; i < 4; i++)
        #pragma unroll
        for (int ni = 0; ni < 4; ni++)
          smem[(wn + ni * 16 + c) * 136 + wm + mi * 16 + q * 4 + i] =
              f2bf(acc[mi][ni][i] + bb[ni]);
    __syncthreads();
    const int b = m0 >> 13;
    const int s0t = m0 & (SEQL - 1);
    const int nl = t >> 1, hh = (t & 1) * 64;
    const int n = n0 + nl, h = n >> 6, d = n & 63;
    #pragma unroll
    for (int u = 0; u < 8; u++)
      *reinterpret_cast<int4*>(&VbT[((size_t)((b * NH + h) * HD + d)) * SEQL + s0t + hh + 8 * u]) =
          *reinterpret_cast<int4*>(&smem[nl * 136 + hh + 8 * u]);
  }
}

// ------------------------------------------------------------- kernel_2 softmax + colsums (fp32)
__global__ __launch_bounds__(256) void k2_softmax_kernel(
    const float* __restrict__ qL, const float* __restrict__ kL,
    float* __restrict__ K2, float* __restrict__ cs)
{
  __shared__ float qs[64 * 65], ks[64 * 65], ps[64 * 65];
  const int t = threadIdx.x, bh = blockIdx.x;
  const int r = t >> 2, cb = (t & 3) << 4;
  #pragma unroll
  for (int i = 0; i < 16; i++) {
    qs[r * 65 + cb + i] = qL[((size_t)bh * LM + r) * HD + cb + i];
    ks[r * 65 + cb + i] = kL[((size_t)bh * LM + r) * HD + cb + i];
  }
  __syncthreads();
  float lg[16] = {};
  for (int d = 0; d < HD; d++) {
    float a = qs[r * 65 + d];
    #pragma unroll
    for (int i = 0; i < 16; i++) lg[i] = fmaf(a, ks[(cb + i) * 65 + d], lg[i]);
  }
  float m = lg[0];
  #pragma unroll
  for (int i = 1; i < 16; i++) m = fmaxf(m, lg[i]);
  m = fmaxf(m, __shfl_xor(m, 1));
  m = fmaxf(m, __shfl_xor(m, 2));
  float s = 0.f;
  #pragma unroll
  for (int i = 0; i < 16; i++) { lg[i] = __expf(lg[i] - m); s += lg[i]; }
  s += __shfl_xor(s, 1);
  s += __shfl_xor(s, 2);
  const float inv = 1.0f / s;
  #pragma unroll
  for (int i = 0; i < 16; i++) {
    float p = lg[i] * inv;
    ps[r * 65 + cb + i] = p;
    K2[((size_t)bh * LM + r) * LM + cb + i] = p;
  }
  __syncthreads();
  if (t < 64) {
    float c = 0.f;
    for (int rr = 0; rr < 64; rr++) c += ps[rr * 65 + t];
    cs[bh * LM + t] = c;
  }
}

// ------------------------------------------------------------- Newton-Schulz inverse (fp32)
__device__ __forceinline__ void mm64(const float* A, const float* B, float* C, int t) {
  const int r = t >> 2, cb = (t & 3) << 4;
  float o[16] = {};
  for (int k = 0; k < 64; k++) {
    float a = A[r * 64 + k];
    #pragma unroll
    for (int i = 0; i < 16; i++) o[i] = fmaf(a, B[k * 64 + cb + i], o[i]);
  }
  #pragma unroll
  for (int i = 0; i < 16; i++) C[r * 64 + cb + i] = o[i];
}

__global__ __launch_bounds__(256) void ns_inverse_kernel(
    const float* __restrict__ K2, const float* __restrict__ cs,
    float* __restrict__ Vi)
{
  __shared__ float Vv[64 * 64], B1[64 * 64], B2[64 * 64], B3[64 * 64];
  const int t = threadIdx.x, bh = blockIdx.x;
  const int r = t >> 2, cb = (t & 3) << 4;

  float m = -1e30f;
  for (int i = t; i < BH * LM; i += 256) m = fmaxf(m, cs[i]);
  B3[t] = m;
  __syncthreads();
  for (int off = 128; off; off >>= 1) {
    if (t < off) B3[t] = fmaxf(B3[t], B3[t + off]);
    __syncthreads();
  }
  const float ginv = 1.0f / B3[0];
  __syncthreads();

  #pragma unroll
  for (int i = 0; i < 16; i++) B1[r * 64 + cb + i] = K2[((size_t)bh * LM + r) * LM + cb + i];
  __syncthreads();
  #pragma unroll
  for (int i = 0; i < 16; i++) Vv[r * 64 + cb + i] = B1[(cb + i) * 64 + r] * ginv;
  __syncthreads();

  for (int it = 0; it < 6; it++) {
    #pragma unroll
    for (int i = 0; i < 16; i++) B1[r * 64 + cb + i] = K2[((size_t)bh * LM + r) * LM + cb + i];
    __syncthreads();
    mm64(B1, Vv, B2, t);
    __syncthreads();
    #pragma unroll
    for (int i = 0; i < 16; i++) {
      int c = cb + i;
      B1[r * 64 + c] = (r == c ? 7.0f : 0.0f) - B2[r * 64 + c];
    }
    __syncthreads();
    mm64(B2, B1, B3, t);
    __syncthreads();
    #pragma unroll
    for (int i = 0; i < 16; i++) {
      int c = cb + i;
      B3[r * 64 + c] = (r == c ? 15.0f : 0.0f) - B3[r * 64 + c];
    }
    __syncthreads();
    mm64(B2, B3, B1, t);
    __syncthreads();
    #pragma unroll
    for (int i = 0; i < 16; i++) {
      int c = cb + i;
      B1[r * 64 + c] = (r == c ? 13.0f : 0.0f) - B1[r * 64 + c];
    }
    __syncthreads();
    mm64(Vv, B1, B3, t);
    __syncthreads();
    #pragma unroll
    for (int i = 0; i < 16; i++) Vv[r * 64 + cb + i] = 0.25f * B3[r * 64 + cb + i];
    __syncthreads();
  }
  #pragma unroll
  for (int i = 0; i < 16; i++) Vi[((size_t)bh * LM + r) * LM + cb + i] = Vv[r * 64 + cb + i];
}

// ------------------------------------------------------------- MFMA kernel_3 @ v (split-K partials)
__global__ __launch_bounds__(256) void k3v_kernel(
    const u16* __restrict__ qLb, const u16* __restrict__ Kb, const u16* __restrict__ VbT,
    float* __restrict__ pnum, float* __restrict__ pden)
{
  __shared__ u16 Ks[64 * 72], Vs[64 * 72], Ps[64 * 72];
  __shared__ float denL[256];
  const int t = threadIdx.x, ch = blockIdx.x, bh = blockIdx.y;
  const int w = t >> 6, lane = t & 63, q = lane >> 4, c = lane & 15;
  const int sr = t >> 2, sp = (t & 3) * 16;

  bf16x8 aq[4][2];
  #pragma unroll
  for (int mi = 0; mi < 4; mi++)
    #pragma unroll
    for (int k2 = 0; k2 < 2; k2++)
      aq[mi][k2] = *reinterpret_cast<const bf16x8*>(
          &qLb[((size_t)bh * LM + mi * 16 + c) * HD + k2 * 32 + q * 8]);

  f32x4 z4 = {0.f, 0.f, 0.f, 0.f};
  f32x4 nacc[4];
  #pragma unroll
  for (int mi = 0; mi < 4; mi++) nacc[mi] = z4;
  float denr[16] = {};

  for (int sub = 0; sub < 8; sub++) {
    const int s0 = ch * CHS + sub * 64;
    __syncthreads();
    #pragma unroll
    for (int u = 0; u < 2; u++) {
      *reinterpret_cast<int4*>(&Ks[sr * 72 + sp + 8 * u]) =
          *reinterpret_cast<const int4*>(&Kb[((size_t)bh * SEQL + s0 + sr) * HD + sp + 8 * u]);
      *reinterpret_cast<int4*>(&Vs[sr * 72 + sp + 8 * u]) =
          *reinterpret_cast<const int4*>(&VbT[((size_t)(bh * HD + sr)) * SEQL + s0 + sp + 8 * u]);
    }
    __syncthreads();
    f32x4 sacc[4];
    #pragma unroll
    for (int mi = 0; mi < 4; mi++) sacc[mi] = z4;
    bf16x8 bk0 = *reinterpret_cast<const bf16x8*>(&Ks[(w * 16 + c) * 72 + q * 8]);
    bf16x8 bk1 = *reinterpret_cast<const bf16x8*>(&Ks[(w * 16 + c) * 72 + 32 + q * 8]);
    #pragma unroll
    for (int mi = 0; mi < 4; mi++) {
      sacc[mi] = MFMA16(aq[mi][0], bk0, sacc[mi]);
      sacc[mi] = MFMA16(aq[mi][1], bk1, sacc[mi]);
    }
    #pragma unroll
    for (int mi = 0; mi < 4; mi++)
      #pragma unroll
      for (int i = 0; i < 4; i++) {
        float p = __expf(sacc[mi][i]);
        denr[mi * 4 + i] += p;
        Ps[(mi * 16 + q * 4 + i) * 72 + w * 16 + c] = f2bf(p);
      }
    __syncthreads();
    #pragma unroll
    for (int k2 = 0; k2 < 2; k2++) {
      bf16x8 bv_ = *reinterpret_cast<const bf16x8*>(&Vs[(w * 16 + c) * 72 + k2 * 32 + q * 8]);
      #pragma unroll
      for (int mi = 0; mi < 4; mi++) {
        bf16x8 ap = *reinterpret_cast<const bf16x8*>(&Ps[(mi * 16 + c) * 72 + k2 * 32 + q * 8]);
        nacc[mi] = MFMA16(ap, bv_, nacc[mi]);
      }
    }
  }
  #pragma unroll
  for (int mi = 0; mi < 4; mi++)
    #pragma unroll
    for (int i = 0; i < 4; i++)
      pnum[(((size_t)bh * NCH + ch) * LM + mi * 16 + q * 4 + i) * HD + w * 16 + c] = nacc[mi][i];
  #pragma unroll
  for (int v = 0; v < 16; v++) {
    denr[v] += __shfl_xor(denr[v], 1);
    denr[v] += __shfl_xor(denr[v], 2);
    denr[v] += __shfl_xor(denr[v], 4);
    denr[v] += __shfl_xor(denr[v], 8);
  }
  if (c == 0) {
    #pragma unroll
    for (int mi = 0; mi < 4; mi++)
      #pragma unroll
      for (int i = 0; i < 4; i++)
        denL[w * 64 + mi * 16 + q * 4 + i] = denr[mi * 4 + i];
  }
  __syncthreads();
  if (t < 64)
    pden[((size_t)bh * NCH + ch) * LM + t] = denL[t] + denL[64 + t] + denL[128 + t] + denL[192 + t];
}

// ------------------------------------------------------------- reduce partials; W2T = (Vi @ normalize(k3 v))^T bf16
__global__ __launch_bounds__(256) void k3v_w2_kernel(
    const float* __restrict__ pnum, const float* __restrict__ pden,
    const float* __restrict__ Vi, u16* __restrict__ W2T)
{
  __shared__ float Vs[64 * 65], Ms[64 * 65], den[64];
  const int t = threadIdx.x, bh = blockIdx.x;
  const int r = t >> 2, cb = (t & 3) << 4;
  #pragma unroll
  for (int i = 0; i < 16; i++) Vs[r * 65 + cb + i] = Vi[((size_t)bh * LM + r) * LM + cb + i];
  float acc[16] = {};
  for (int ch = 0; ch < NCH; ch++) {
    const float* p = pnum + (((size_t)bh * NCH + ch) * LM + r) * HD + cb;
    #pragma unroll
    for (int i = 0; i < 16; i++) acc[i] += p[i];
  }
  if ((t & 3) == 0) {
    float d = 0.f;
    for (int ch = 0; ch < NCH; ch++) d += pden[((size_t)bh * NCH + ch) * LM + r];
    den[r] = d;
  }
  __syncthreads();
  const float dinv = 1.0f / den[r];
  #pragma unroll
  for (int i = 0; i < 16; i++) Ms[r * 65 + cb + i] = acc[i] * dinv;
  __syncthreads();
  float o[16] = {};
  for (int k = 0; k < 64; k++) {
    float a = Vs[r * 65 + k];
    #pragma unroll
    for (int i = 0; i < 16; i++) o[i] = fmaf(a, Ms[k * 65 + cb + i], o[i]);
  }
  #pragma unroll
  for (int i = 0; i < 16; i++)
    W2T[((size_t)bh * HD + cb + i) * LM + r] = f2bf(o[i]);
}

// ------------------------------------------------------------- MFMA kernel_1 softmax @ W2
__global__ __launch_bounds__(256) void final_kernel(
    const u16* __restrict__ Qb, const u16* __restrict__ kLb, const u16* __restrict__ W2T,
    u16* __restrict__ pre)
{
  __shared__ u16 Ps[64 * 72];
  __shared__ float mxL[256], smL[256];
  const int t = threadIdx.x, st = blockIdx.x, bh = blockIdx.y;
  const int w = t >> 6, lane = t & 63, q = lane >> 4, c = lane & 15;
  const int sb = st * 64;

  bf16x8 aq[4][2], bkL[2], bw2[2];
  #pragma unroll
  for (int mi = 0; mi < 4; mi++)
    #pragma unroll
    for (int k2 = 0; k2 < 2; k2++)
      aq[mi][k2] = *reinterpret_cast<const bf16x8*>(
          &Qb[((size_t)bh * SEQL + sb + mi * 16 + c) * HD + k2 * 32 + q * 8]);
  #pragma unroll
  for (int k2 = 0; k2 < 2; k2++) {
    bkL[k2] = *reinterpret_cast<const bf16x8*>(
        &kLb[((size_t)bh * LM + w * 16 + c) * HD + k2 * 32 + q * 8]);
    bw2[k2] = *reinterpret_cast<const bf16x8*>(
        &W2T[((size_t)bh * HD + w * 16 + c) * LM + k2 * 32 + q * 8]);
  }

  f32x4 z4 = {0.f, 0.f, 0.f, 0.f};
  f32x4 sacc[4];
  #pragma unroll
  for (int mi = 0; mi < 4; mi++) sacc[mi] = z4;
  #pragma unroll
  for (int k2 = 0; k2 < 2; k2++)
    #pragma unroll
    for (int mi = 0; mi < 4; mi++)
      sacc[mi] = MFMA16(aq[mi][k2], bkL[k2], sacc[mi]);

  float mx[16];
  #pragma unroll
  for (int v = 0; v < 16; v++) {
    mx[v] = sacc[v >> 2][v & 3];
    mx[v] = fmaxf(mx[v], __shfl_xor(mx[v], 1));
    mx[v] = fmaxf(mx[v], __shfl_xor(mx[v], 2));
    mx[v] = fmaxf(mx[v], __shfl_xor(mx[v], 4));
    mx[v] = fmaxf(mx[v], __shfl_xor(mx[v], 8));
  }
  if (c == 0) {
    #pragma unroll
    for (int mi = 0; mi < 4; mi++)
      #pragma unroll
      for (int i = 0; i < 4; i++)
        mxL[w * 64 + mi * 16 + q * 4 + i] = mx[mi * 4 + i];
  }
  __syncthreads();
  float p[16], dn[16];
  #pragma unroll
  for (int mi = 0; mi < 4; mi++)
    #pragma unroll
    for (int i = 0; i < 4; i++) {
      int row = mi * 16 + q * 4 + i;
      float M = fmaxf(fmaxf(mxL[row], mxL[64 + row]), fmaxf(mxL[128 + row], mxL[192 + row]));
      float pp = __expf(sacc[mi][i] - M);
      p[mi * 4 + i] = pp;
      dn[mi * 4 + i] = pp;
    }
  #pragma unroll
  for (int v = 0; v < 16; v++) {
    dn[v] += __shfl_xor(dn[v], 1);
    dn[v] += __shfl_xor(dn[v], 2);
    dn[v] += __shfl_xor(dn[v], 4);
    dn[v] += __shfl_xor(dn[v], 8);
  }
  if (c == 0) {
    #pragma unroll
    for (int mi = 0; mi < 4; mi++)
      #pragma unroll
      for (int i = 0; i < 4; i++)
        smL[w * 64 + mi * 16 + q * 4 + i] = dn[mi * 4 + i];
  }
  #pragma unroll
  for (int mi = 0; mi < 4; mi++)
    #pragma unroll
    for (int i = 0; i < 4; i++)
      Ps[(mi * 16 + q * 4 + i) * 72 + w * 16 + c] = f2bf(p[mi * 4 + i]);
  __syncthreads();

  f32x4 oacc[4];
  #pragma unroll
  for (int mi = 0; mi < 4; mi++) oacc[mi] = z4;
  #pragma unroll
  for (int k2 = 0; k2 < 2; k2++)
    #pragma unroll
    for (int mi = 0; mi < 4; mi++) {
      bf16x8 ap = *reinterpret_cast<const bf16x8*>(&Ps[(mi * 16 + c) * 72 + k2 * 32 + q * 8]);
      oacc[mi] = MFMA16(ap, bw2[k2], oacc[mi]);
    }
  #pragma unroll
  for (int mi = 0; mi < 4; mi++)
    #pragma unroll
    for (int i = 0; i < 4; i++) {
      int row = mi * 16 + q * 4 + i;
      float den = smL[row] + smL[64 + row] + smL[128 + row] + smL[192 + row];
      float v = oacc[mi][i] / den;
      pre[((size_t)((bh >> 3) * SEQL + sb + row)) * EMB + (bh & 7) * HD + w * 16 + c] = f2bf(v);
    }
}

// ------------------------------------------------------------- MFMA out = pre @ Wo + bo
__global__ __launch_bounds__(256) void out_proj_kernel(
    const u16* __restrict__ pre, const u16* __restrict__ WoT, const void* bo,
    const int* flag, void* out)
{
  __shared__ u16 As[128 * 72];
  __shared__ u16 Bs[128 * 72];
  const int t = threadIdx.x;
  const int m0 = blockIdx.x * 128, n0 = blockIdx.y * 128;
  const int isf32 = flag[0];
  const int w = t >> 6, lane = t & 63, q = lane >> 4, c = lane & 15;
  const int wm = (w >> 1) * 64, wn = (w & 1) * 64;
  const int sr = t >> 1, sh = (t & 1) * 32;

  f32x4 acc[4][4];
  f32x4 z4 = {0.f, 0.f, 0.f, 0.f};
  #pragma unroll
  for (int mi = 0; mi < 4; mi++)
    #pragma unroll
    for (int ni = 0; ni < 4; ni++) acc[mi][ni] = z4;

  for (int k0 = 0; k0 < EMB; k0 += 64) {
    __syncthreads();
    #pragma unroll
    for (int u = 0; u < 4; u++) {
      *reinterpret_cast<int4*>(&As[sr * 72 + sh + 8 * u]) =
          *reinterpret_cast<const int4*>(&pre[(size_t)(m0 + sr) * EMB + k0 + sh + 8 * u]);
      *reinterpret_cast<int4*>(&Bs[sr * 72 + sh + 8 * u]) =
          *reinterpret_cast<const int4*>(&WoT[(size_t)(n0 + sr) * EMB + k0 + sh + 8 * u]);
    }
    __syncthreads();
    #pragma unroll
    for (int kk = 0; kk < 64; kk += 32) {
      bf16x8 af[4], bfv[4];
      #pragma unroll
      for (int mi = 0; mi < 4; mi++)
        af[mi] = *reinterpret_cast<const bf16x8*>(&As[(wm + mi * 16 + c) * 72 + kk + q * 8]);
      #pragma unroll
      for (int ni = 0; ni < 4; ni++)
        bfv[ni] = *reinterpret_cast<const bf16x8*>(&Bs[(wn + ni * 16 + c) * 72 + kk + q * 8]);
      #pragma unroll
      for (int mi = 0; mi < 4; mi++)
        #pragma unroll
        for (int ni = 0; ni < 4; ni++)
          acc[mi][ni] = MFMA16(af[mi], bfv[ni], acc[mi][ni]);
    }
  }
  float bb[4];
  #pragma unroll
  for (int ni = 0; ni < 4; ni++) bb[ni] = load1_any(bo, n0 + wn + ni * 16 + c, isf32);
  #pragma unroll
  for (int mi = 0; mi < 4; mi++)
    #pragma unroll
    for (int i = 0; i < 4; i++) {
      int m = m0 + wm + mi * 16 + q * 4 + i;
      #pragma unroll
      for (int ni = 0; ni < 4; ni++) {
        int n = n0 + wn + ni * 16 + c;
        float v = acc[mi][ni][i] + bb[ni];
        if (isf32) ((float*)out)[(size_t)m * EMB + n] = v;
        else       ((u16*)out)[(size_t)m * EMB + n] = f2bf(v);
      }
    }
}

// ------------------------------------------------------------- launch
extern "C" void kernel_launch(void* const* d_in, const int* in_sizes, int n_in,
                              void* d_out, int out_size, void* d_ws, size_t ws_size,
                              hipStream_t stream)
{
  (void)in_sizes; (void)n_in; (void)out_size; (void)ws_size;
  const void* x  = d_in[0];
  const void* Wq = d_in[1];
  const void* bq = d_in[2];
  const void* Wk = d_in[3];
  const void* bk = d_in[4];
  const void* Wv = d_in[5];
  const void* bv = d_in[6];
  const void* Wo = d_in[7];
  const void* bo = d_in[8];

  float* ws = (float*)d_ws;
  int*   flag  = (int*)ws;                         // 64 floats
  float* xmean = ws + 64;                          // 131072
  float* qL    = xmean + 131072;                   // 131072
  float* kL    = qL + 131072;                      // 131072
  float* K2    = kL + 131072;                      // 131072
  float* cs    = K2 + 131072;                      // 2048
  float* Vi    = cs + 2048;                        // 131072
  float* pnum  = Vi + 131072;                      // 2097152
  float* pden  = pnum + 2097152;                   // 32768
  u16* WqT = (u16*)(pden + 32768);                 // 262144 u16 each
  u16* WkT = WqT + 262144;
  u16* WvT = WkT + 262144;
  u16* WoT = WvT + 262144;
  u16* qLb = WoT + 262144;                         // 131072
  u16* kLb = qLb + 131072;                         // 131072
  u16* W2T = kLb + 131072;                         // 131072
  u16* Qb  = W2T + 131072;                         // 16777216
  u16* Kb  = Qb + 16777216;                        // 16777216
  u16* VbT = Kb + 16777216;                        // 16777216
  u16* pre = Kb;  // alias: Kb dead after k3v_kernel; final runs after k3v_w2
  // total ws: ~11.2 MB fp32 + ~103.5 MB bf16 = ~115 MB

  probe_kernel<<<1, 256, 0, stream>>>(x, flag);
  prep_wt_kernel<<<256, 256, 0, stream>>>(Wq, Wk, Wv, Wo, flag, WqT, WkT, WvT, WoT);
  xmean_kernel<<<BS * LM, 256, 0, stream>>>(x, flag, xmean);
  lm_proj_kernel<<<dim3(4, 8, 2), 256, 0, stream>>>(xmean, Wq, bq, Wk, bk, flag, qL, kL, qLb, kLb);
  proj_qkv_kernel<<<dim3(256, 4, 3), 256, 0, stream>>>(x, WqT, WkT, WvT, bq, bk, bv, flag, Qb, Kb, VbT);
  k2_softmax_kernel<<<BH, 256, 0, stream>>>(qL, kL, K2, cs);
  ns_inverse_kernel<<<BH, 256, 0, stream>>>(K2, cs, Vi);
  k3v_kernel<<<dim3(NCH, BH), 256, 0, stream>>>(qLb, Kb, VbT, pnum, pden);
  k3v_w2_kernel<<<BH, 256, 0, stream>>>(pnum, pden, Vi, W2T);
  final_kernel<<<dim3(SEQL / 64, BH), 256, 0, stream>>>(Qb, kLb, W2T, pre);
  out_proj_kernel<<<dim3(256, 4), 256, 0, stream>>>(pre, WoT, bo, flag, d_out);
}